// Round 7
// baseline (1558.729 us; speedup 1.0000x reference)
//
#include <hip/hip_runtime.h>
#include <stdint.h>

typedef long long ll;
typedef unsigned short u16;
typedef __attribute__((ext_vector_type(8))) short bf16x8;
typedef __attribute__((ext_vector_type(4))) float f32x4;

// ---------- edge-index dtype detection (int64 vs int32, decided on device) ----------
__device__ inline bool ei_is64(const void* ei) {
  const int* p = (const int*)ei;
  return ((p[1] | p[3] | p[5] | p[7]) == 0);
}
__device__ inline int ei_at(const void* ei, ll i, bool is64) {
  return is64 ? (int)((const ll*)ei)[i] : ((const int*)ei)[i];
}

// ---------- helpers ----------
__device__ inline float fast_tanh(float x) {
  x = fminf(15.f, fmaxf(-15.f, x));
  float e2 = __expf(2.f * x);
  return (e2 - 1.f) / (e2 + 1.f);
}
__device__ inline float fast_sigmoid(float x) { return 1.f / (1.f + __expf(-x)); }

__device__ inline float bf2f(u16 u) {
  union { unsigned int i; float f; } v; v.i = ((unsigned int)u) << 16; return v.f;
}
__device__ inline u16 f2bf(float f) {
  union { float f; unsigned int i; } v; v.f = f;
  unsigned int r = v.i + 0x7FFFu + ((v.i >> 16) & 1u);  // RNE
  return (u16)(r >> 16);
}

// ---------- degree pipeline ----------
__global__ void k_init(float* deg, int* cursor, int n) {
  int i = blockIdx.x * blockDim.x + threadIdx.x;
  if (i < n) { deg[i] = 1.0f; cursor[i] = 0; }
}
__global__ void k_edge_deg(const void* __restrict__ ei, ll E, float* deg) {
  ll i = (ll)blockIdx.x * blockDim.x + threadIdx.x;
  if (i >= E) return;
  bool is64 = ei_is64(ei);
  atomicAdd(&deg[ei_at(ei, E + i, is64)], 1.0f);
}
__global__ void k_fin_deg(const float* __restrict__ deg, float* __restrict__ isd,
                          float* __restrict__ invd, int n) {
  int i = blockIdx.x * blockDim.x + threadIdx.x;
  if (i < n) {
    float d = deg[i];
    isd[i] = rsqrtf(d);
    invd[i] = 1.0f / d;
  }
}

// ---------- 3-kernel prefix scan over in-degrees ----------
__global__ __launch_bounds__(1024) void k_scan1(const float* __restrict__ deg,
                                                int* __restrict__ rowp,
                                                int* __restrict__ part, int n) {
  __shared__ int sm[1024];
  int b = blockIdx.x, tid = threadIdx.x;
  int i = b * 1024 + tid;
  int v = (i < n) ? ((int)deg[i] - 1) : 0;
  sm[tid] = v;
  __syncthreads();
  for (int off = 1; off < 1024; off <<= 1) {
    int t = (tid >= off) ? sm[tid - off] : 0;
    __syncthreads();
    sm[tid] += t;
    __syncthreads();
  }
  if (i < n) rowp[i + 1] = sm[tid];
  if (tid == 1023) part[b] = sm[1023];
}
__global__ void k_scan2(const int* __restrict__ part, int* __restrict__ offs, int nb) {
  __shared__ int sm[128];
  int t = threadIdx.x;
  int v = (t < nb) ? part[t] : 0;
  sm[t] = v;
  __syncthreads();
  for (int off = 1; off < 128; off <<= 1) {
    int u = (t >= off) ? sm[t - off] : 0;
    __syncthreads();
    sm[t] += u;
    __syncthreads();
  }
  offs[t] = sm[t] - v;  // exclusive
}
__global__ __launch_bounds__(1024) void k_scan3(int* __restrict__ rowp,
                                                const int* __restrict__ offs, int n) {
  int i = blockIdx.x * 1024 + threadIdx.x;
  if (i == 0) rowp[0] = 0;
  if (i < n) rowp[i + 1] += offs[blockIdx.x];
}

// ---------- CSR fill ----------
__global__ void k_fill(const void* __restrict__ ei, ll E,
                       const int* __restrict__ rowp, int* __restrict__ cursor,
                       int* __restrict__ col, float* __restrict__ w,
                       const float* __restrict__ isd) {
  ll i = (ll)blockIdx.x * blockDim.x + threadIdx.x;
  if (i >= E) return;
  bool is64 = ei_is64(ei);
  int s = ei_at(ei, i, is64);
  int d = ei_at(ei, E + i, is64);
  int pos = rowp[d] + atomicAdd(&cursor[d], 1);
  col[pos] = s;
  w[pos] = isd[s] * isd[d];
}

// ---------- weight transpose + bf16: Wt[n][k] = bf16(W[k][n]) ----------
__global__ void k_wt(const float* __restrict__ W, u16* __restrict__ Wt, int K, int N) {
  int t = blockIdx.x * blockDim.x + threadIdx.x;
  if (t >= K * N) return;
  int k = t % K, n = t / K;
  Wt[t] = f2bf(W[(size_t)k * N + n]);
}
// classifier weights: Wct[128][128], rows >= N zero-padded
__global__ void k_wtc(const float* __restrict__ W, u16* __restrict__ Wt, int K, int N) {
  int t = blockIdx.x * blockDim.x + threadIdx.x;
  if (t >= 128 * K) return;
  int k = t % K, n = t / K;
  Wt[t] = (n < N) ? f2bf(W[(size_t)k * N + n]) : (u16)0;
}

// ---------- CSR gather aggregation, fused diag + optional bias/tanh ----------
// out[d, 0:F] = act( invd[d]*in[d,:] + sum_j w_j * in[col_j,:] + bias ); F = 4<<lgC
// EPI: 0 none, 1 tanh(v+bias). OBF: 1 -> bf16 out, else fp32. OB2: also bf16 to out2.
template <int EPI, int OBF, int OB2>
__global__ void k_gather(const int* __restrict__ rowp, const int* __restrict__ col,
                         const float* __restrict__ w,
                         const float* __restrict__ in, int ldin,
                         const float* __restrict__ invd, const float* __restrict__ bias,
                         void* __restrict__ outv, u16* __restrict__ out2,
                         int n, int lgC) {
  ll gid = (ll)blockIdx.x * blockDim.x + threadIdx.x;
  ll total = (ll)n << lgC;
  if (gid >= total) return;
  int d = (int)(gid >> lgC);
  int c4 = (int)(gid & ((1 << lgC) - 1));
  float4 acc;
  {
    float4 v = *(const float4*)(in + (size_t)d * ldin + c4 * 4);
    float s = invd[d];
    acc.x = v.x * s; acc.y = v.y * s; acc.z = v.z * s; acc.w = v.w * s;
  }
  int b = rowp[d], e = rowp[d + 1];
  for (int j = b; j < e; ++j) {
    int s = col[j];
    float wt = w[j];
    float4 v = *(const float4*)(in + (size_t)s * ldin + c4 * 4);
    acc.x += wt * v.x; acc.y += wt * v.y; acc.z += wt * v.z; acc.w += wt * v.w;
  }
  if (EPI == 1) {
    int c = c4 * 4;
    acc.x = fast_tanh(acc.x + bias[c + 0]);
    acc.y = fast_tanh(acc.y + bias[c + 1]);
    acc.z = fast_tanh(acc.z + bias[c + 2]);
    acc.w = fast_tanh(acc.w + bias[c + 3]);
  }
  if (OBF) {
    ushort4 o;
    o.x = f2bf(acc.x); o.y = f2bf(acc.y); o.z = f2bf(acc.z); o.w = f2bf(acc.w);
    ((ushort4*)outv)[gid] = o;
  } else {
    ((float4*)outv)[gid] = acc;
  }
  if (OB2) {
    ushort4 o;
    o.x = f2bf(acc.x); o.y = f2bf(acc.y); o.z = f2bf(acc.z); o.w = f2bf(acc.w);
    ((ushort4*)out2)[gid] = o;
  }
}

// ---------- MFMA bf16 GEMM with XCD-swizzled 1-D grid + internal col-tile loop ----------
// C[M, *] = op(A[M,K]bf16 @ Bt[cols][K]bf16).
// Grid: 8*SPX*CPB blocks (1-D). Decode: xcd=bid&7, j=bid>>3, by=xcd*SPX+j/CPB,
// bx=j%CPB (guard by<GZ). Block = 4 row-stacked waves: rows [by*256, by*256+256).
// Block covers CT consecutive 64-col tiles at c0=(bx*CT+ct)*64 — A-stripe re-read
// comes from the block's own XCD L2 (stripe <= 512 KB), and same-stripe blocks are
// co-located on one XCD by the swizzle, so the stripe is fetched from HBM once.
// CACC: 1 -> C += (fp32 RMW). EPI: 1 tanh(v+bias), 2 sigmoid(v+bias). OBF: bf16 store.
// CG: guard gc < NC on the epilogue (classifier tail).
template <int CPB, int CT, int CACC, int EPI, int OBF, bool CG>
__global__ __launch_bounds__(256) void k_mfma(const u16* __restrict__ A, int ldA,
                                              const u16* __restrict__ Bt, int ldB,
                                              const float* __restrict__ bias,
                                              void* __restrict__ Cv, int ldC,
                                              int M, int K, int SPX, int GZ, int NC) {
  int bid = blockIdx.x;
  int xcd = bid & 7, j = bid >> 3;
  int by = xcd * SPX + j / CPB;
  int bx = j % CPB;
  if (by >= GZ) return;

  const int lane = threadIdx.x & 63;
  const int wid = threadIdx.x >> 6;
  const int r0 = by * 256 + wid * 64;
  const int lr = lane & 15;
  const int kb = (lane >> 4) * 8;

  const u16* ap[4];
#pragma unroll
  for (int fm = 0; fm < 4; ++fm) {
    int r = r0 + fm * 16 + lr;
    if (r > M - 1) r = M - 1;  // clamp tail rows (stores guarded)
    ap[fm] = A + (size_t)r * ldA + kb;
  }

  const int orow = (lane >> 4) * 4;
  const int ocol = lane & 15;

  for (int ct = 0; ct < CT; ++ct) {
    const int c0 = (bx * CT + ct) * 64;
    f32x4 acc[4][4];
#pragma unroll
    for (int i = 0; i < 4; ++i)
#pragma unroll
      for (int jj = 0; jj < 4; ++jj) acc[i][jj] = (f32x4)0.f;

    const u16* bp[4];
#pragma unroll
    for (int fn = 0; fn < 4; ++fn) bp[fn] = Bt + (size_t)(c0 + fn * 16 + lr) * ldB + kb;

    for (int k0 = 0; k0 < K; k0 += 32) {
      bf16x8 a[4], b[4];
#pragma unroll
      for (int i = 0; i < 4; ++i) a[i] = *(const bf16x8*)(ap[i] + k0);
#pragma unroll
      for (int i = 0; i < 4; ++i) b[i] = *(const bf16x8*)(bp[i] + k0);
#pragma unroll
      for (int fm = 0; fm < 4; ++fm)
#pragma unroll
        for (int fn = 0; fn < 4; ++fn)
          acc[fm][fn] = __builtin_amdgcn_mfma_f32_16x16x32_bf16(a[fm], b[fn], acc[fm][fn], 0, 0, 0);
    }

    // C/D mapping: col = lane&15, row = (lane>>4)*4 + j (m89-verified)
#pragma unroll
    for (int fm = 0; fm < 4; ++fm) {
#pragma unroll
      for (int jj = 0; jj < 4; ++jj) {
        int gr = r0 + fm * 16 + orow + jj;
        if (gr >= M) continue;
#pragma unroll
        for (int fn = 0; fn < 4; ++fn) {
          int gc = c0 + fn * 16 + ocol;
          if (CG && gc >= NC) continue;
          float v = acc[fm][fn][jj];
          size_t off = (size_t)gr * ldC + gc;
          if (CACC) v += ((const float*)Cv)[off];
          if (EPI == 1) v = fast_tanh(v + bias[gc]);
          if (EPI == 2) v = fast_sigmoid(v + bias[gc]);
          if (OBF) ((u16*)Cv)[off] = f2bf(v);
          else     ((float*)Cv)[off] = v;
        }
      }
    }
  }
}

// ---------- launch ----------
static inline int cdiv(ll a, ll b) { return (int)((a + b - 1) / b); }

extern "C" void kernel_launch(void* const* d_in, const int* in_sizes, int n_in,
                              void* d_out, int out_size, void* d_ws, size_t ws_size,
                              hipStream_t stream) {
  const float* x  = (const float*)d_in[0];
  const void*  ei = d_in[1];
  const float* W1 = (const float*)d_in[2];
  const float* b1 = (const float*)d_in[3];
  const float* W2 = (const float*)d_in[4];
  const float* b2 = (const float*)d_in[5];
  const float* W3 = (const float*)d_in[6];
  const float* b3 = (const float*)d_in[7];
  const float* Wc = (const float*)d_in[8];
  const float* bc = (const float*)d_in[9];

  const int Nn = in_sizes[0] / 256;  // 100000
  const ll  E  = in_sizes[1] / 2;    // 400000

  // ===== d_ws: 256.0 MB (proven): h1 bf16 [N,1024] | q3 fp32 [N,128] =====
  // After last q-chunk GEMM h1 dies; its region is reused for:
  //   hb bf16 [N,128] (25.6 MB, classifier input) | Wct bf16 [128][128] @ +32 MB
  u16*   h1  = (u16*)d_ws;
  float* q3  = (float*)((char*)d_ws + (size_t)Nn * 2048);
  u16*   hb  = (u16*)d_ws;                               // reuses dead h1
  u16*   Wct = (u16*)((char*)d_ws + 32u * 1024 * 1024);  // reuses dead h1

  // ===== d_out scratch (22.8M floats), liveness-scheduled =====
  // [0,3N): deg|isd|invd (invd live thru L3 gather; dead before cls writes outf)
  // [3N,~1.73M): rowp|cursor|colx|wgt|part|offs|W1t|W2t|W3t (dead before cls)
  // stA @1.8M (12.8M fl): L1 Sx-bf16 / q_c fp32      (dead before L3 gather)
  // stB @14.6M (6.4M fl): h2_c bf16                  (dead before L3 gather)
  // final: outf [0,100N) | hout [100N, 228N)
  float* ob     = (float*)d_out;
  float* deg    = ob;
  float* isd    = ob + Nn;
  float* invd   = ob + 2 * (size_t)Nn;
  int*   rowp   = (int*)(ob + 3 * (size_t)Nn);
  int*   cursor = (int*)(ob + 4 * (size_t)Nn + 4);
  int*   colx   = (int*)(ob + 5 * (size_t)Nn + 8);
  float* wgt    = ob + 5 * (size_t)Nn + 8 + E;
  int*   part   = (int*)(ob + 5 * (size_t)Nn + 8 + 2 * E);
  int*   offs   = part + 128;
  u16*   W1t    = (u16*)(offs + 128);                   // [1024][256]
  u16*   W2t    = W1t + 1024 * 256;                     // [512][1024]
  u16*   W3t    = W2t + 512 * 1024;                     // [128][512]
  float* stA    = ob + 1800000;                         // 12.8M floats
  u16*   stB    = (u16*)(ob + 14600000);                // 12.8M u16
  float* outf   = ob;                                   // [N,100]
  float* hout   = ob + (size_t)Nn * 100;                // [N,128] fp32 (output 2)

  const int T = 256;
  const int GZ = cdiv(Nn, 256);        // 391 row-blocks of 256
  const int SPX = cdiv(GZ, 8);         // stripes per XCD (49)
  const int SB = cdiv(Nn, 1024);       // scan blocks (98)

  // ---- degrees + CSR + weight conversion ----
  k_init<<<cdiv(Nn, T), T, 0, stream>>>(deg, cursor, Nn);
  k_edge_deg<<<cdiv(E, T), T, 0, stream>>>(ei, E, deg);
  k_fin_deg<<<cdiv(Nn, T), T, 0, stream>>>(deg, isd, invd, Nn);
  k_scan1<<<SB, 1024, 0, stream>>>(deg, rowp, part, Nn);
  k_scan2<<<1, 128, 0, stream>>>(part, offs, SB);
  k_scan3<<<SB, 1024, 0, stream>>>(rowp, offs, Nn);
  k_fill<<<cdiv(E, T), T, 0, stream>>>(ei, E, rowp, cursor, colx, wgt, isd);
  k_wt<<<cdiv(256 * 1024, T), T, 0, stream>>>(W1, W1t, 256, 1024);
  k_wt<<<cdiv(1024 * 512, T), T, 0, stream>>>(W2, W2t, 1024, 512);
  k_wt<<<cdiv(512 * 128, T), T, 0, stream>>>(W3, W3t, 512, 128);

  // ---- layer 1: Sx = S x (bf16), h1 = tanh(Sx @ W1 + b1) (bf16, MFMA) ----
  {
    ll t4 = (ll)Nn * 64;  // F=256
    k_gather<0, 1, 0><<<cdiv(t4, T), T, 0, stream>>>(rowp, colx, wgt, x, 256, invd,
                                                     nullptr, stA, nullptr, Nn, 6);
    // 1024 cols = CPB 4 x CT 4; stripe 256x256 bf16 = 128 KB stays in XCD L2
    k_mfma<4, 4, 0, 1, 1, false><<<8 * SPX * 4, T, 0, stream>>>(
        (const u16*)stA, 256, W1t, 256, b1, h1, 1024, Nn, 256, SPX, GZ, 1024);
  }

  // ---- layer 2 (4 col-chunks of 128) fused with layer-3 GEMM:
  //      q_c = h1@W2[:,c]; h2_c = tanh(S q_c + b2_c) bf16; q3 (+)= h2_c @ W3[c,:] ----
  for (int c = 0; c < 4; ++c) {
    const int c0 = c * 128;
    // 128 cols = CPB 2 x CT 1; stripe 256x1024 bf16 = 512 KB, pair co-located on XCD
    k_mfma<2, 1, 0, 0, 0, false><<<8 * SPX * 2, T, 0, stream>>>(
        h1, 1024, W2t + (size_t)c0 * 1024, 1024, nullptr, stA, 128, Nn, 1024, SPX, GZ, 128);
    ll t4 = (ll)Nn * 32;  // F=128
    k_gather<1, 1, 0><<<cdiv(t4, T), T, 0, stream>>>(rowp, colx, wgt, stA, 128, invd,
                                                     b2 + c0, stB, nullptr, Nn, 5);
    if (c == 0)
      k_mfma<2, 1, 0, 0, 0, false><<<8 * SPX * 2, T, 0, stream>>>(
          stB, 128, W3t + c0, 512, nullptr, q3, 128, Nn, 128, SPX, GZ, 128);
    else
      k_mfma<2, 1, 1, 0, 0, false><<<8 * SPX * 2, T, 0, stream>>>(
          stB, 128, W3t + c0, 512, nullptr, q3, 128, Nn, 128, SPX, GZ, 128);
  }

  // ---- layer 3 aggregation: h3 = tanh(S q3 + b3) -> hout fp32 + hb bf16 ----
  {
    ll t4 = (ll)Nn * 32;
    k_gather<1, 0, 1><<<cdiv(t4, T), T, 0, stream>>>(rowp, colx, wgt, q3, 128, invd,
                                                     b3, hout, hb, Nn, 5);
  }

  // ---- classifier: out = sigmoid(hb @ Wc + bc) (MFMA, guarded N=100 tail) ----
  {
    k_wtc<<<cdiv(128 * 128, T), T, 0, stream>>>(Wc, Wct, 128, 100);
    k_mfma<2, 1, 0, 2, 0, true><<<8 * SPX * 2, T, 0, stream>>>(
        hb, 128, Wct, 128, bc, outf, 100, Nn, 128, SPX, GZ, 100);
  }
}

// Round 8
// 1285.233 us; speedup vs baseline: 1.2128x; 1.2128x over previous
//
#include <hip/hip_runtime.h>
#include <stdint.h>

typedef long long ll;
typedef unsigned short u16;
typedef __attribute__((ext_vector_type(8))) short bf16x8;
typedef __attribute__((ext_vector_type(4))) float f32x4;

// ---------- edge-index dtype detection (int64 vs int32, decided on device) ----------
__device__ inline bool ei_is64(const void* ei) {
  const int* p = (const int*)ei;
  return ((p[1] | p[3] | p[5] | p[7]) == 0);
}
__device__ inline int ei_at(const void* ei, ll i, bool is64) {
  return is64 ? (int)((const ll*)ei)[i] : ((const int*)ei)[i];
}

// ---------- helpers ----------
__device__ inline float fast_tanh(float x) {
  x = fminf(15.f, fmaxf(-15.f, x));
  float e2 = __expf(2.f * x);
  return (e2 - 1.f) / (e2 + 1.f);
}
__device__ inline float fast_sigmoid(float x) { return 1.f / (1.f + __expf(-x)); }

__device__ inline float bf2f(u16 u) {
  union { unsigned int i; float f; } v; v.i = ((unsigned int)u) << 16; return v.f;
}
__device__ inline u16 f2bf(float f) {
  union { float f; unsigned int i; } v; v.f = f;
  unsigned int r = v.i + 0x7FFFu + ((v.i >> 16) & 1u);  // RNE
  return (u16)(r >> 16);
}

// async global->LDS, 16B per lane; lds dest = wave-uniform base + lane*16
__device__ inline void gload16(const u16* g, void* l) {
  __builtin_amdgcn_global_load_lds(
      (const __attribute__((address_space(1))) unsigned int*)(const void*)g,
      (__attribute__((address_space(3))) unsigned int*)l, 16, 0, 0);
}

// ---------- degree pipeline ----------
__global__ void k_init(float* deg, int* cursor, int n) {
  int i = blockIdx.x * blockDim.x + threadIdx.x;
  if (i < n) { deg[i] = 1.0f; cursor[i] = 0; }
}
__global__ void k_edge_deg(const void* __restrict__ ei, ll E, float* deg) {
  ll i = (ll)blockIdx.x * blockDim.x + threadIdx.x;
  if (i >= E) return;
  bool is64 = ei_is64(ei);
  atomicAdd(&deg[ei_at(ei, E + i, is64)], 1.0f);
}
__global__ void k_fin_deg(const float* __restrict__ deg, float* __restrict__ isd,
                          float* __restrict__ invd, int n) {
  int i = blockIdx.x * blockDim.x + threadIdx.x;
  if (i < n) {
    float d = deg[i];
    isd[i] = rsqrtf(d);
    invd[i] = 1.0f / d;
  }
}

// ---------- 3-kernel prefix scan over in-degrees ----------
__global__ __launch_bounds__(1024) void k_scan1(const float* __restrict__ deg,
                                                int* __restrict__ rowp,
                                                int* __restrict__ part, int n) {
  __shared__ int sm[1024];
  int b = blockIdx.x, tid = threadIdx.x;
  int i = b * 1024 + tid;
  int v = (i < n) ? ((int)deg[i] - 1) : 0;
  sm[tid] = v;
  __syncthreads();
  for (int off = 1; off < 1024; off <<= 1) {
    int t = (tid >= off) ? sm[tid - off] : 0;
    __syncthreads();
    sm[tid] += t;
    __syncthreads();
  }
  if (i < n) rowp[i + 1] = sm[tid];
  if (tid == 1023) part[b] = sm[1023];
}
__global__ void k_scan2(const int* __restrict__ part, int* __restrict__ offs, int nb) {
  __shared__ int sm[128];
  int t = threadIdx.x;
  int v = (t < nb) ? part[t] : 0;
  sm[t] = v;
  __syncthreads();
  for (int off = 1; off < 128; off <<= 1) {
    int u = (t >= off) ? sm[t - off] : 0;
    __syncthreads();
    sm[t] += u;
    __syncthreads();
  }
  offs[t] = sm[t] - v;  // exclusive
}
__global__ __launch_bounds__(1024) void k_scan3(int* __restrict__ rowp,
                                                const int* __restrict__ offs, int n) {
  int i = blockIdx.x * 1024 + threadIdx.x;
  if (i == 0) rowp[0] = 0;
  if (i < n) rowp[i + 1] += offs[blockIdx.x];
}

// ---------- CSR fill ----------
__global__ void k_fill(const void* __restrict__ ei, ll E,
                       const int* __restrict__ rowp, int* __restrict__ cursor,
                       int* __restrict__ col, float* __restrict__ w,
                       const float* __restrict__ isd) {
  ll i = (ll)blockIdx.x * blockDim.x + threadIdx.x;
  if (i >= E) return;
  bool is64 = ei_is64(ei);
  int s = ei_at(ei, i, is64);
  int d = ei_at(ei, E + i, is64);
  int pos = rowp[d] + atomicAdd(&cursor[d], 1);
  col[pos] = s;
  w[pos] = isd[s] * isd[d];
}

// ---------- weight transpose + bf16: Wt[n][k] = bf16(W[k][n]) ----------
__global__ void k_wt(const float* __restrict__ W, u16* __restrict__ Wt, int K, int N) {
  int t = blockIdx.x * blockDim.x + threadIdx.x;
  if (t >= K * N) return;
  int k = t % K, n = t / K;
  Wt[t] = f2bf(W[(size_t)k * N + n]);
}
// classifier weights: Wct[128][128], rows >= N zero-padded
__global__ void k_wtc(const float* __restrict__ W, u16* __restrict__ Wt, int K, int N) {
  int t = blockIdx.x * blockDim.x + threadIdx.x;
  if (t >= 128 * K) return;
  int k = t % K, n = t / K;
  Wt[t] = (n < N) ? f2bf(W[(size_t)k * N + n]) : (u16)0;
}

// ---------- CSR gather aggregation, fused diag + optional bias/tanh ----------
// out[d, 0:F] = act( invd[d]*in[d,:] + sum_j w_j * in[col_j,:] + bias ); F = 4<<lgC
// EPI: 0 none, 1 tanh(v+bias). OBF: 1 -> bf16 out, else fp32. OB2: also bf16 to out2.
template <int EPI, int OBF, int OB2>
__global__ void k_gather(const int* __restrict__ rowp, const int* __restrict__ col,
                         const float* __restrict__ w,
                         const float* __restrict__ in, int ldin,
                         const float* __restrict__ invd, const float* __restrict__ bias,
                         void* __restrict__ outv, u16* __restrict__ out2,
                         int n, int lgC) {
  ll gid = (ll)blockIdx.x * blockDim.x + threadIdx.x;
  ll total = (ll)n << lgC;
  if (gid >= total) return;
  int d = (int)(gid >> lgC);
  int c4 = (int)(gid & ((1 << lgC) - 1));
  float4 acc;
  {
    float4 v = *(const float4*)(in + (size_t)d * ldin + c4 * 4);
    float s = invd[d];
    acc.x = v.x * s; acc.y = v.y * s; acc.z = v.z * s; acc.w = v.w * s;
  }
  int b = rowp[d], e = rowp[d + 1];
  for (int j = b; j < e; ++j) {
    int s = col[j];
    float wt = w[j];
    float4 v = *(const float4*)(in + (size_t)s * ldin + c4 * 4);
    acc.x += wt * v.x; acc.y += wt * v.y; acc.z += wt * v.z; acc.w += wt * v.w;
  }
  if (EPI == 1) {
    int c = c4 * 4;
    acc.x = fast_tanh(acc.x + bias[c + 0]);
    acc.y = fast_tanh(acc.y + bias[c + 1]);
    acc.z = fast_tanh(acc.z + bias[c + 2]);
    acc.w = fast_tanh(acc.w + bias[c + 3]);
  }
  if (OBF) {
    ushort4 o;
    o.x = f2bf(acc.x); o.y = f2bf(acc.y); o.z = f2bf(acc.z); o.w = f2bf(acc.w);
    ((ushort4*)outv)[gid] = o;
  } else {
    ((float4*)outv)[gid] = acc;
  }
  if (OB2) {
    ushort4 o;
    o.x = f2bf(acc.x); o.y = f2bf(acc.y); o.z = f2bf(acc.z); o.w = f2bf(acc.w);
    ((ushort4*)out2)[gid] = o;
  }
}

// ---------- MFMA bf16 GEMM, LDS-staged A (m97 structure) ----------
// C[M,*] = op(A[M,K]bf16 @ Bt[cols][K]bf16).
// Block 256 thr = 4 waves (2x2); tile BM=128 x BN=128; wave 64x64 (4x4 frags).
// A-tile 128x64 bf16 staged via global_load_lds w16, double-buffered (32 KB),
// 16B-slot XOR swizzle (slot^=row&7) applied on the GLOBAL source (m173) and on
// the ds_read address -> conflict-free. B direct from global (L2-resident weights).
// Grid 8*SPX*CPB (1-D, XCD swizzle): xcd=bid&7, j=bid>>3, by=xcd*SPX+j/CPB,
// bx=j%CPB (guard by<GZ) -> same-stripe col-blocks co-resident on one XCD.
// CACC: 1 -> C += (fp32 RMW). EPI: 1 tanh(v+bias), 2 sigmoid(v+bias).
// OBF: bf16 store. CG: guard gc < NC (classifier tail). K must be mult of 64.
template <int CPB, int CACC, int EPI, int OBF, bool CG>
__global__ __launch_bounds__(256) void k_mfma2(const u16* __restrict__ A, int ldA,
                                               const u16* __restrict__ Bt, int ldB,
                                               const float* __restrict__ bias,
                                               void* __restrict__ Cv, int ldC,
                                               int M, int K, int SPX, int GZ, int NC) {
  int bid = blockIdx.x;
  int xcd = bid & 7, j = bid >> 3;
  int by = xcd * SPX + j / CPB;
  int bx = j % CPB;
  if (by >= GZ) return;

  __shared__ char As[2 * 16384];  // 2 x (128 rows x 64 bf16)

  const int tid = threadIdx.x;
  const int lane = tid & 63;
  const int w = tid >> 6;
  const int wm = w >> 1, wn = w & 1;
  const int rb = by * 128;                 // block row base
  const int c0 = bx * 128 + wn * 64;       // wave col base
  const int lr = lane & 15;
  const int kg = lane >> 4;                // k-group 0..3

  // accumulators
  f32x4 acc[4][4];
#pragma unroll
  for (int i = 0; i < 4; ++i)
#pragma unroll
    for (int jj = 0; jj < 4; ++jj) acc[i][jj] = (f32x4)0.f;

  // B fragment pointers (per-lane row = output col)
  const u16* bp[4];
#pragma unroll
  for (int fn = 0; fn < 4; ++fn)
    bp[fn] = Bt + (size_t)(c0 + fn * 16 + lr) * ldB + kg * 8;

  // ds_read offsets for A frags: row in tile, swizzled 16B slot
  int aoff[2][4];
#pragma unroll
  for (int ks = 0; ks < 2; ++ks)
#pragma unroll
    for (int fm = 0; fm < 4; ++fm) {
      int row = wm * 64 + fm * 16 + lr;
      int slot = (ks * 4 + kg) ^ (row & 7);
      aoff[ks][fm] = row * 128 + slot * 16;
    }

  // staging lambda: tile (rb.., k0..k0+64) -> LDS buf, pre-swizzled source
  auto STAGE = [&](int buf, int k0) {
#pragma unroll
    for (int it = 0; it < 4; ++it) {
      int li = it * 256 + tid;        // 16B-slot linear index 0..1023
      int row = li >> 3;              // 0..127
      int slot = li & 7;
      int gr = rb + row;
      if (gr > M - 1) gr = M - 1;     // clamp tail (stores guarded)
      int gk = k0 + ((slot ^ (row & 7)) << 3);
      char* dst = As + buf * 16384 + it * 4096 + w * 1024;  // wave-uniform
      gload16(A + (size_t)gr * ldA + gk, dst);
    }
  };

  const int nt = K >> 6;
  STAGE(0, 0);
  __syncthreads();
  int cur = 0;
  for (int t = 0; t < nt; ++t) {
    if (t + 1 < nt) STAGE(cur ^ 1, (t + 1) << 6);
    const char* ab = As + cur * 16384;
    const int k0 = t << 6;
#pragma unroll
    for (int ks = 0; ks < 2; ++ks) {
      bf16x8 a[4], b[4];
#pragma unroll
      for (int i = 0; i < 4; ++i) a[i] = *(const bf16x8*)(ab + aoff[ks][i]);
#pragma unroll
      for (int i = 0; i < 4; ++i) b[i] = *(const bf16x8*)(bp[i] + k0 + ks * 32);
#pragma unroll
      for (int fm = 0; fm < 4; ++fm)
#pragma unroll
        for (int fn = 0; fn < 4; ++fn)
          acc[fm][fn] = __builtin_amdgcn_mfma_f32_16x16x32_bf16(a[fm], b[fn], acc[fm][fn], 0, 0, 0);
    }
    __syncthreads();
    cur ^= 1;
  }

  // epilogue: C/D mapping col = lane&15, row = (lane>>4)*4 + j (m89-verified)
  const int orow = kg * 4;
  const int ocol = lane & 15;
#pragma unroll
  for (int fm = 0; fm < 4; ++fm) {
#pragma unroll
    for (int jj = 0; jj < 4; ++jj) {
      int gr = rb + wm * 64 + fm * 16 + orow + jj;
      if (gr >= M) continue;
#pragma unroll
      for (int fn = 0; fn < 4; ++fn) {
        int gc = c0 + fn * 16 + ocol;
        if (CG && gc >= NC) continue;
        float v = acc[fm][fn][jj];
        size_t off = (size_t)gr * ldC + gc;
        if (CACC) v += ((const float*)Cv)[off];
        if (EPI == 1) v = fast_tanh(v + bias[gc]);
        if (EPI == 2) v = fast_sigmoid(v + bias[gc]);
        if (OBF) ((u16*)Cv)[off] = f2bf(v);
        else     ((float*)Cv)[off] = v;
      }
    }
  }
}

// ---------- launch ----------
static inline int cdiv(ll a, ll b) { return (int)((a + b - 1) / b); }

extern "C" void kernel_launch(void* const* d_in, const int* in_sizes, int n_in,
                              void* d_out, int out_size, void* d_ws, size_t ws_size,
                              hipStream_t stream) {
  const float* x  = (const float*)d_in[0];
  const void*  ei = d_in[1];
  const float* W1 = (const float*)d_in[2];
  const float* b1 = (const float*)d_in[3];
  const float* W2 = (const float*)d_in[4];
  const float* b2 = (const float*)d_in[5];
  const float* W3 = (const float*)d_in[6];
  const float* b3 = (const float*)d_in[7];
  const float* Wc = (const float*)d_in[8];
  const float* bc = (const float*)d_in[9];

  const int Nn = in_sizes[0] / 256;  // 100000
  const ll  E  = in_sizes[1] / 2;    // 400000

  // ===== d_ws: 256.0 MB (proven): h1 bf16 [N,1024] | q3 fp32 [N,128] =====
  // After last q-chunk GEMM h1 dies; region reused: hb bf16 [N,128] | Wct @ +32MB
  u16*   h1  = (u16*)d_ws;
  float* q3  = (float*)((char*)d_ws + (size_t)Nn * 2048);
  u16*   hb  = (u16*)d_ws;
  u16*   Wct = (u16*)((char*)d_ws + 32u * 1024 * 1024);

  // ===== d_out scratch (22.8M floats), liveness-scheduled (same map as r7) =====
  float* ob     = (float*)d_out;
  float* deg    = ob;
  float* isd    = ob + Nn;
  float* invd   = ob + 2 * (size_t)Nn;
  int*   rowp   = (int*)(ob + 3 * (size_t)Nn);
  int*   cursor = (int*)(ob + 4 * (size_t)Nn + 4);
  int*   colx   = (int*)(ob + 5 * (size_t)Nn + 8);
  float* wgt    = ob + 5 * (size_t)Nn + 8 + E;
  int*   part   = (int*)(ob + 5 * (size_t)Nn + 8 + 2 * E);
  int*   offs   = part + 128;
  u16*   W1t    = (u16*)(offs + 128);                   // [1024][256]
  u16*   W2t    = W1t + 1024 * 256;                     // [512][1024]
  u16*   W3t    = W2t + 512 * 1024;                     // [128][512]
  float* stA    = ob + 1800000;                         // 12.8M floats
  u16*   stB    = (u16*)(ob + 14600000);                // 12.8M u16
  float* outf   = ob;                                   // [N,100]
  float* hout   = ob + (size_t)Nn * 100;                // [N,128] fp32 (output 2)

  const int T = 256;
  const int GZ = cdiv(Nn, 128);        // 782 row-stripes of 128
  const int SPX = cdiv(GZ, 8);         // 98 stripes per XCD
  const int SB = cdiv(Nn, 1024);       // scan blocks (98)

  // ---- degrees + CSR + weight conversion ----
  k_init<<<cdiv(Nn, T), T, 0, stream>>>(deg, cursor, Nn);
  k_edge_deg<<<cdiv(E, T), T, 0, stream>>>(ei, E, deg);
  k_fin_deg<<<cdiv(Nn, T), T, 0, stream>>>(deg, isd, invd, Nn);
  k_scan1<<<SB, 1024, 0, stream>>>(deg, rowp, part, Nn);
  k_scan2<<<1, 128, 0, stream>>>(part, offs, SB);
  k_scan3<<<SB, 1024, 0, stream>>>(rowp, offs, Nn);
  k_fill<<<cdiv(E, T), T, 0, stream>>>(ei, E, rowp, cursor, colx, wgt, isd);
  k_wt<<<cdiv(256 * 1024, T), T, 0, stream>>>(W1, W1t, 256, 1024);
  k_wt<<<cdiv(1024 * 512, T), T, 0, stream>>>(W2, W2t, 1024, 512);
  k_wt<<<cdiv(512 * 128, T), T, 0, stream>>>(W3, W3t, 512, 128);

  // ---- layer 1: Sx = S x (bf16), h1 = tanh(Sx @ W1 + b1) (MFMA, LDS-staged) ----
  {
    ll t4 = (ll)Nn * 64;  // F=256
    k_gather<0, 1, 0><<<cdiv(t4, T), T, 0, stream>>>(rowp, colx, wgt, x, 256, invd,
                                                     nullptr, stA, nullptr, Nn, 6);
    // 1024 cols = 8 col-blocks co-located per stripe (stripe 128x256bf16 = 64 KB in L2)
    k_mfma2<8, 0, 1, 1, false><<<8 * SPX * 8, T, 0, stream>>>(
        (const u16*)stA, 256, W1t, 256, b1, h1, 1024, Nn, 256, SPX, GZ, 1024);
  }

  // ---- layer 2 (4 col-chunks of 128) fused with layer-3 GEMM:
  //      q_c = h1@W2[:,c]; h2_c = tanh(S q_c + b2_c) bf16; q3 (+)= h2_c @ W3[c,:] ----
  for (int c = 0; c < 4; ++c) {
    const int c0 = c * 128;
    k_mfma2<1, 0, 0, 0, false><<<8 * SPX, T, 0, stream>>>(
        h1, 1024, W2t + (size_t)c0 * 1024, 1024, nullptr, stA, 128, Nn, 1024, SPX, GZ, 128);
    ll t4 = (ll)Nn * 32;  // F=128
    k_gather<1, 1, 0><<<cdiv(t4, T), T, 0, stream>>>(rowp, colx, wgt, stA, 128, invd,
                                                     b2 + c0, stB, nullptr, Nn, 5);
    if (c == 0)
      k_mfma2<1, 0, 0, 0, false><<<8 * SPX, T, 0, stream>>>(
          stB, 128, W3t + c0, 512, nullptr, q3, 128, Nn, 128, SPX, GZ, 128);
    else
      k_mfma2<1, 1, 0, 0, false><<<8 * SPX, T, 0, stream>>>(
          stB, 128, W3t + c0, 512, nullptr, q3, 128, Nn, 128, SPX, GZ, 128);
  }

  // ---- layer 3 aggregation: h3 = tanh(S q3 + b3) -> hout fp32 + hb bf16 ----
  {
    ll t4 = (ll)Nn * 32;
    k_gather<1, 0, 1><<<cdiv(t4, T), T, 0, stream>>>(rowp, colx, wgt, q3, 128, invd,
                                                     b3, hout, hb, Nn, 5);
  }

  // ---- classifier: out = sigmoid(hb @ Wc + bc) (MFMA, guarded N=100 tail) ----
  {
    k_wtc<<<cdiv(128 * 128, T), T, 0, stream>>>(Wc, Wct, 128, 100);
    k_mfma2<1, 0, 2, 0, true><<<8 * SPX, T, 0, stream>>>(
        hb, 128, Wct, 128, bc, outf, 100, Nn, 128, SPX, GZ, 100);
  }
}

// Round 9
// 1050.869 us; speedup vs baseline: 1.4833x; 1.2230x over previous
//
#include <hip/hip_runtime.h>
#include <stdint.h>

typedef long long ll;
typedef unsigned short u16;
typedef __attribute__((ext_vector_type(8))) short bf16x8;
typedef __attribute__((ext_vector_type(4))) float f32x4;

// ---------- edge-index dtype detection (int64 vs int32, decided on device) ----------
__device__ inline bool ei_is64(const void* ei) {
  const int* p = (const int*)ei;
  return ((p[1] | p[3] | p[5] | p[7]) == 0);
}
__device__ inline int ei_at(const void* ei, ll i, bool is64) {
  return is64 ? (int)((const ll*)ei)[i] : ((const int*)ei)[i];
}

// ---------- helpers ----------
__device__ inline float fast_tanh(float x) {
  x = fminf(15.f, fmaxf(-15.f, x));
  float e2 = __expf(2.f * x);
  return (e2 - 1.f) / (e2 + 1.f);
}
__device__ inline float fast_sigmoid(float x) { return 1.f / (1.f + __expf(-x)); }

__device__ inline float bf2f(u16 u) {
  union { unsigned int i; float f; } v; v.i = ((unsigned int)u) << 16; return v.f;
}
__device__ inline u16 f2bf(float f) {
  union { float f; unsigned int i; } v; v.f = f;
  unsigned int r = v.i + 0x7FFFu + ((v.i >> 16) & 1u);  // RNE
  return (u16)(r >> 16);
}

// async global->LDS, 16B per lane; lds dest = wave-uniform base + lane*16
__device__ inline void gload16(const u16* g, void* l) {
  __builtin_amdgcn_global_load_lds(
      (const __attribute__((address_space(1))) unsigned int*)(const void*)g,
      (__attribute__((address_space(3))) unsigned int*)l, 16, 0, 0);
}

// ---------- degree pipeline ----------
__global__ void k_init(float* deg, int* cursor, int n) {
  int i = blockIdx.x * blockDim.x + threadIdx.x;
  if (i < n) { deg[i] = 1.0f; cursor[i] = 0; }
}
__global__ void k_edge_deg(const void* __restrict__ ei, ll E, float* deg) {
  ll i = (ll)blockIdx.x * blockDim.x + threadIdx.x;
  if (i >= E) return;
  bool is64 = ei_is64(ei);
  atomicAdd(&deg[ei_at(ei, E + i, is64)], 1.0f);
}
__global__ void k_fin_deg(const float* __restrict__ deg, float* __restrict__ isd,
                          float* __restrict__ invd, int n) {
  int i = blockIdx.x * blockDim.x + threadIdx.x;
  if (i < n) {
    float d = deg[i];
    isd[i] = rsqrtf(d);
    invd[i] = 1.0f / d;
  }
}

// ---------- 3-kernel prefix scan over in-degrees ----------
__global__ __launch_bounds__(1024) void k_scan1(const float* __restrict__ deg,
                                                int* __restrict__ rowp,
                                                int* __restrict__ part, int n) {
  __shared__ int sm[1024];
  int b = blockIdx.x, tid = threadIdx.x;
  int i = b * 1024 + tid;
  int v = (i < n) ? ((int)deg[i] - 1) : 0;
  sm[tid] = v;
  __syncthreads();
  for (int off = 1; off < 1024; off <<= 1) {
    int t = (tid >= off) ? sm[tid - off] : 0;
    __syncthreads();
    sm[tid] += t;
    __syncthreads();
  }
  if (i < n) rowp[i + 1] = sm[tid];
  if (tid == 1023) part[b] = sm[1023];
}
__global__ void k_scan2(const int* __restrict__ part, int* __restrict__ offs, int nb) {
  __shared__ int sm[128];
  int t = threadIdx.x;
  int v = (t < nb) ? part[t] : 0;
  sm[t] = v;
  __syncthreads();
  for (int off = 1; off < 128; off <<= 1) {
    int u = (t >= off) ? sm[t - off] : 0;
    __syncthreads();
    sm[t] += u;
    __syncthreads();
  }
  offs[t] = sm[t] - v;  // exclusive
}
__global__ __launch_bounds__(1024) void k_scan3(int* __restrict__ rowp,
                                                const int* __restrict__ offs, int n) {
  int i = blockIdx.x * 1024 + threadIdx.x;
  if (i == 0) rowp[0] = 0;
  if (i < n) rowp[i + 1] += offs[blockIdx.x];
}

// ---------- CSR fill ----------
__global__ void k_fill(const void* __restrict__ ei, ll E,
                       const int* __restrict__ rowp, int* __restrict__ cursor,
                       int* __restrict__ col, float* __restrict__ w,
                       const float* __restrict__ isd) {
  ll i = (ll)blockIdx.x * blockDim.x + threadIdx.x;
  if (i >= E) return;
  bool is64 = ei_is64(ei);
  int s = ei_at(ei, i, is64);
  int d = ei_at(ei, E + i, is64);
  int pos = rowp[d] + atomicAdd(&cursor[d], 1);
  col[pos] = s;
  w[pos] = isd[s] * isd[d];
}

// ---------- weight transpose + bf16: Wt[n][k] = bf16(W[k][n]) ----------
__global__ void k_wt(const float* __restrict__ W, u16* __restrict__ Wt, int K, int N) {
  int t = blockIdx.x * blockDim.x + threadIdx.x;
  if (t >= K * N) return;
  int k = t % K, n = t / K;
  Wt[t] = f2bf(W[(size_t)k * N + n]);
}
// classifier weights: Wct[128][128], rows >= N zero-padded
__global__ void k_wtc(const float* __restrict__ W, u16* __restrict__ Wt, int K, int N) {
  int t = blockIdx.x * blockDim.x + threadIdx.x;
  if (t >= 128 * K) return;
  int k = t % K, n = t / K;
  Wt[t] = (n < N) ? f2bf(W[(size_t)k * N + n]) : (u16)0;
}

// ---------- CSR gather aggregation, fused diag + optional bias/tanh ----------
// out[d, 0:F] = act( invd[d]*in[d,:] + sum_j w_j * in[col_j,:] + bias ); F = 4<<lgC
// EPI: 0 none, 1 tanh(v+bias). OBF: 1 bf16 out else fp32. OB2: also bf16 to out2.
// IBF: 1 -> input is bf16 (u16), else fp32.  ldin in ELEMENTS of the input type.
template <int EPI, int OBF, int OB2, int IBF>
__global__ void k_gather(const int* __restrict__ rowp, const int* __restrict__ col,
                         const float* __restrict__ w,
                         const void* __restrict__ inv, int ldin,
                         const float* __restrict__ invd, const float* __restrict__ bias,
                         void* __restrict__ outv, u16* __restrict__ out2,
                         int n, int lgC) {
  ll gid = (ll)blockIdx.x * blockDim.x + threadIdx.x;
  ll total = (ll)n << lgC;
  if (gid >= total) return;
  int d = (int)(gid >> lgC);
  int c4 = (int)(gid & ((1 << lgC) - 1));

  auto load4 = [&](int r) -> float4 {
    if (IBF) {
      ushort4 uv = *(const ushort4*)((const u16*)inv + (size_t)r * ldin + c4 * 4);
      float4 f;
      f.x = bf2f(uv.x); f.y = bf2f(uv.y); f.z = bf2f(uv.z); f.w = bf2f(uv.w);
      return f;
    } else {
      return *(const float4*)((const float*)inv + (size_t)r * ldin + c4 * 4);
    }
  };

  float4 acc;
  {
    float4 v = load4(d);
    float s = invd[d];
    acc.x = v.x * s; acc.y = v.y * s; acc.z = v.z * s; acc.w = v.w * s;
  }
  int b = rowp[d], e = rowp[d + 1];
  for (int j = b; j < e; ++j) {
    int s = col[j];
    float wt = w[j];
    float4 v = load4(s);
    acc.x += wt * v.x; acc.y += wt * v.y; acc.z += wt * v.z; acc.w += wt * v.w;
  }
  if (EPI == 1) {
    int c = c4 * 4;
    acc.x = fast_tanh(acc.x + bias[c + 0]);
    acc.y = fast_tanh(acc.y + bias[c + 1]);
    acc.z = fast_tanh(acc.z + bias[c + 2]);
    acc.w = fast_tanh(acc.w + bias[c + 3]);
  }
  if (OBF) {
    ushort4 o;
    o.x = f2bf(acc.x); o.y = f2bf(acc.y); o.z = f2bf(acc.z); o.w = f2bf(acc.w);
    ((ushort4*)outv)[gid] = o;
  } else {
    ((float4*)outv)[gid] = acc;
  }
  if (OB2) {
    ushort4 o;
    o.x = f2bf(acc.x); o.y = f2bf(acc.y); o.z = f2bf(acc.z); o.w = f2bf(acc.w);
    ((ushort4*)out2)[gid] = o;
  }
}

// ---------- MFMA bf16 GEMM, full m97 structure: A AND B LDS-staged ----------
// C[M,*] = op(A[M,K]bf16 @ Bt[cols][K]bf16); Bt is k-major like A -> symmetric staging.
// Block 256 thr = 4 waves (2x2); tile 128x128; wave 64x64 (4x4 frags 16x16x32).
// Per K-tile (BK=64): A-tile 128x64 + B-tile 128x64 staged via global_load_lds w16,
// both double-buffered (64 KB LDS total), 16B-slot XOR swizzle (slot^=row&7) applied
// on the GLOBAL source (m173) and on the ds_read address -> conflict-free b128 reads.
// One vmcnt(0)+barrier per K-tile absorbs ALL staging latency (A and B).
// Grid 8*SPX*CPB (XCD swizzle): xcd=bid&7, j=bid>>3, by=xcd*SPX+j/CPB, bx=j%CPB.
// CACC: 1 -> C += (fp32 RMW). EPI: 1 tanh(v+bias), 2 sigmoid(v+bias).
// OBF: bf16 store. CG: guard gc<NC. K mult of 64; cols mult of 128.
template <int CPB, int CACC, int EPI, int OBF, bool CG>
__global__ __launch_bounds__(256) void k_mfma2(const u16* __restrict__ A, int ldA,
                                               const u16* __restrict__ Bt, int ldB,
                                               const float* __restrict__ bias,
                                               void* __restrict__ Cv, int ldC,
                                               int M, int K, int SPX, int GZ, int NC) {
  int bid = blockIdx.x;
  int xcd = bid & 7, j0 = bid >> 3;
  int by = xcd * SPX + j0 / CPB;
  int bx = j0 % CPB;
  if (by >= GZ) return;  // block-uniform: no barrier divergence

  __shared__ char LdsA[32768];  // 2 bufs x (128 rows x 64 bf16)
  __shared__ char LdsB[32768];

  const int tid = threadIdx.x;
  const int lane = tid & 63;
  const int w = tid >> 6;
  const int wm = w >> 1, wn = w & 1;
  const int rb = by * 128;
  const int cb = bx * 128;
  const int c0 = cb + wn * 64;
  const int lr = lane & 15;
  const int kg = lane >> 4;

  f32x4 acc[4][4];
#pragma unroll
  for (int i = 0; i < 4; ++i)
#pragma unroll
    for (int jj = 0; jj < 4; ++jj) acc[i][jj] = (f32x4)0.f;

  // lane-local ds byte offset within one 16 KB tile, per k-slice ks (row&7 == lr&7)
  int alane[2];
#pragma unroll
  for (int ks = 0; ks < 2; ++ks)
    alane[ks] = lr * 128 + (((ks * 4 + kg) ^ (lr & 7)) * 16);

  // staging: thread covers slot (tid&7) of rows (tid>>3) + it*32; pre-swizzled source
  const int srow = tid >> 3;
  const int sk = ((tid & 7) ^ (srow & 7)) * 8;  // element offset within K-tile
  const u16* aSrc[4];
#pragma unroll
  for (int it = 0; it < 4; ++it) {
    int gr = rb + it * 32 + srow;
    if (gr > M - 1) gr = M - 1;  // clamp tail rows (stores guarded)
    aSrc[it] = A + (size_t)gr * ldA + sk;
  }
  const u16* bSrc = Bt + (size_t)(cb + srow) * ldB + sk;
  const size_t bStep = (size_t)32 * ldB;

  auto STAGE = [&](int buf, int k0) {
#pragma unroll
    for (int it = 0; it < 4; ++it) {
      gload16(aSrc[it] + k0, LdsA + buf * 16384 + it * 4096 + w * 1024);
      gload16(bSrc + (size_t)it * bStep + k0, LdsB + buf * 16384 + it * 4096 + w * 1024);
    }
  };

  auto COMPUTE = [&](int buf) {
    const char* ab = LdsA + buf * 16384 + ((wm * 64) << 7);
    const char* bb = LdsB + buf * 16384 + ((wn * 64) << 7);
#pragma unroll
    for (int ks = 0; ks < 2; ++ks) {
      bf16x8 a[4], b[4];
#pragma unroll
      for (int i = 0; i < 4; ++i) a[i] = *(const bf16x8*)(ab + (i << 11) + alane[ks]);
#pragma unroll
      for (int i = 0; i < 4; ++i) b[i] = *(const bf16x8*)(bb + (i << 11) + alane[ks]);
#pragma unroll
      for (int fm = 0; fm < 4; ++fm)
#pragma unroll
        for (int fn = 0; fn < 4; ++fn)
          acc[fm][fn] = __builtin_amdgcn_mfma_f32_16x16x32_bf16(a[fm], b[fn], acc[fm][fn], 0, 0, 0);
    }
  };

  const int nt = K >> 6;
  STAGE(0, 0);
  __syncthreads();
  for (int t = 0; t < nt; ++t) {
    if (t + 1 < nt) STAGE((t + 1) & 1, (t + 1) << 6);
    COMPUTE(t & 1);
    __syncthreads();
  }

  // epilogue: C/D mapping col = lane&15, row = (lane>>4)*4 + j (m89-verified)
  const int orow = kg * 4;
  const int ocol = lane & 15;
#pragma unroll
  for (int fm = 0; fm < 4; ++fm) {
#pragma unroll
    for (int jj = 0; jj < 4; ++jj) {
      int gr = rb + wm * 64 + fm * 16 + orow + jj;
      if (gr >= M) continue;
#pragma unroll
      for (int fn = 0; fn < 4; ++fn) {
        int gc = c0 + fn * 16 + ocol;
        if (CG && gc >= NC) continue;
        float v = acc[fm][fn][jj];
        size_t off = (size_t)gr * ldC + gc;
        if (CACC) v += ((const float*)Cv)[off];
        if (EPI == 1) v = fast_tanh(v + bias[gc]);
        if (EPI == 2) v = fast_sigmoid(v + bias[gc]);
        if (OBF) ((u16*)Cv)[off] = f2bf(v);
        else     ((float*)Cv)[off] = v;
      }
    }
  }
}

// ---------- launch ----------
static inline int cdiv(ll a, ll b) { return (int)((a + b - 1) / b); }

extern "C" void kernel_launch(void* const* d_in, const int* in_sizes, int n_in,
                              void* d_out, int out_size, void* d_ws, size_t ws_size,
                              hipStream_t stream) {
  const float* x  = (const float*)d_in[0];
  const void*  ei = d_in[1];
  const float* W1 = (const float*)d_in[2];
  const float* b1 = (const float*)d_in[3];
  const float* W2 = (const float*)d_in[4];
  const float* b2 = (const float*)d_in[5];
  const float* W3 = (const float*)d_in[6];
  const float* b3 = (const float*)d_in[7];
  const float* Wc = (const float*)d_in[8];
  const float* bc = (const float*)d_in[9];

  const int Nn = in_sizes[0] / 256;  // 100000
  const ll  E  = in_sizes[1] / 2;    // 400000

  // ===== d_ws: 256.0 MB (proven): h1 bf16 [N,1024] | q3 fp32 [N,128] =====
  // After last q-GEMM h1 dies; region reused: hb bf16 [N,128] | Wct @ +32MB
  u16*   h1  = (u16*)d_ws;
  float* q3  = (float*)((char*)d_ws + (size_t)Nn * 2048);
  u16*   hb  = (u16*)d_ws;
  u16*   Wct = (u16*)((char*)d_ws + 32u * 1024 * 1024);

  // ===== d_out scratch (22.8M floats), liveness-scheduled =====
  // [0,3N): deg|isd|invd (invd live thru L3 gather; dead before cls writes outf)
  // [3N,~1.73M): rowp|cursor|colx|wgt|part|offs|W1t|W2t|W3t (dead before cls)
  // qc  @1.8M  (12.8M fl): L1 Sx bf16 [N,256] / L2 q_c bf16 [N,256] (dead pre-L3-gather)
  // h2s @14.6M (6.4M fl):  h2 sub-block bf16 [N,128]              (dead pre-L3-gather)
  // final: outf [0,100N) | hout [100N,228N)
  float* ob     = (float*)d_out;
  float* deg    = ob;
  float* isd    = ob + Nn;
  float* invd   = ob + 2 * (size_t)Nn;
  int*   rowp   = (int*)(ob + 3 * (size_t)Nn);
  int*   cursor = (int*)(ob + 4 * (size_t)Nn + 4);
  int*   colx   = (int*)(ob + 5 * (size_t)Nn + 8);
  float* wgt    = ob + 5 * (size_t)Nn + 8 + E;
  int*   part   = (int*)(ob + 5 * (size_t)Nn + 8 + 2 * E);
  int*   offs   = part + 128;
  u16*   W1t    = (u16*)(offs + 128);                   // [1024][256]
  u16*   W2t    = W1t + 1024 * 256;                     // [512][1024]
  u16*   W3t    = W2t + 512 * 1024;                     // [128][512]
  u16*   qc     = (u16*)(ob + 1800000);                 // [N,256] bf16 (also L1 Sx)
  u16*   h2s    = (u16*)(ob + 14600000);                // [N,128] bf16
  float* outf   = ob;                                   // [N,100]
  float* hout   = ob + (size_t)Nn * 100;                // [N,128] fp32 (output 2)

  const int T = 256;
  const int GZ = cdiv(Nn, 128);        // 782 row-stripes of 128
  const int SPX = cdiv(GZ, 8);         // 98 stripes per XCD
  const int SB = cdiv(Nn, 1024);       // scan blocks (98)

  // ---- degrees + CSR + weight conversion ----
  k_init<<<cdiv(Nn, T), T, 0, stream>>>(deg, cursor, Nn);
  k_edge_deg<<<cdiv(E, T), T, 0, stream>>>(ei, E, deg);
  k_fin_deg<<<cdiv(Nn, T), T, 0, stream>>>(deg, isd, invd, Nn);
  k_scan1<<<SB, 1024, 0, stream>>>(deg, rowp, part, Nn);
  k_scan2<<<1, 128, 0, stream>>>(part, offs, SB);
  k_scan3<<<SB, 1024, 0, stream>>>(rowp, offs, Nn);
  k_fill<<<cdiv(E, T), T, 0, stream>>>(ei, E, rowp, cursor, colx, wgt, isd);
  k_wt<<<cdiv(256 * 1024, T), T, 0, stream>>>(W1, W1t, 256, 1024);
  k_wt<<<cdiv(1024 * 512, T), T, 0, stream>>>(W2, W2t, 1024, 512);
  k_wt<<<cdiv(512 * 128, T), T, 0, stream>>>(W3, W3t, 512, 128);

  // ---- layer 1: Sx = S x (bf16), h1 = tanh(Sx @ W1 + b1) (MFMA, A+B LDS) ----
  {
    ll t4 = (ll)Nn * 64;  // F=256
    k_gather<0, 1, 0, 0><<<cdiv(t4, T), T, 0, stream>>>(rowp, colx, wgt, x, 256, invd,
                                                        nullptr, qc, nullptr, Nn, 6);
    k_mfma2<8, 0, 1, 1, false><<<8 * SPX * 8, T, 0, stream>>>(
        qc, 256, W1t, 256, b1, h1, 1024, Nn, 256, SPX, GZ, 1024);
  }

  // ---- layer 2, 2 col-chunks of 256, fused with layer-3 GEMM in 128-col sub-blocks:
  //      q_c = h1@W2[:,c] (bf16); per sub s: h2s = tanh(S q_c[:,s] + b2) bf16;
  //      q3 (+)= h2s @ W3[k-slice,:]  (fp32 RMW) ----
  for (int c = 0; c < 2; ++c) {
    k_mfma2<2, 0, 0, 1, false><<<8 * SPX * 2, T, 0, stream>>>(
        h1, 1024, W2t + (size_t)(c * 256) * 1024, 1024, nullptr, qc, 256, Nn, 1024,
        SPX, GZ, 256);
    for (int s = 0; s < 2; ++s) {
      const int k0 = c * 256 + s * 128;
      ll t4 = (ll)Nn * 32;  // F=128
      k_gather<1, 1, 0, 1><<<cdiv(t4, T), T, 0, stream>>>(
          rowp, colx, wgt, qc + s * 128, 256, invd, b2 + k0, h2s, nullptr, Nn, 5);
      if (k0 == 0)
        k_mfma2<1, 0, 0, 0, false><<<8 * SPX, T, 0, stream>>>(
            h2s, 128, W3t + k0, 512, nullptr, q3, 128, Nn, 128, SPX, GZ, 128);
      else
        k_mfma2<1, 1, 0, 0, false><<<8 * SPX, T, 0, stream>>>(
            h2s, 128, W3t + k0, 512, nullptr, q3, 128, Nn, 128, SPX, GZ, 128);
    }
  }

  // ---- layer 3 aggregation: h3 = tanh(S q3 + b3) -> hout fp32 + hb bf16 ----
  {
    ll t4 = (ll)Nn * 32;
    k_gather<1, 0, 1, 0><<<cdiv(t4, T), T, 0, stream>>>(rowp, colx, wgt, q3, 128, invd,
                                                        b3, hout, hb, Nn, 5);
  }

  // ---- classifier: out = sigmoid(hb @ Wct + bc) (MFMA, guarded N=100 tail) ----
  {
    k_wtc<<<cdiv(128 * 128, T), T, 0, stream>>>(Wc, Wct, 128, 100);
    k_mfma2<1, 0, 2, 0, true><<<8 * SPX, T, 0, stream>>>(
        hb, 128, Wct, 128, bc, outf, 100, Nn, 128, SPX, GZ, 100);
  }
}